// Round 15
// baseline (204.012 us; speedup 1.0000x reference)
//
#include <hip/hip_runtime.h>
#include <hip/hip_bf16.h>

static constexpr int Bn = 8, Cc = 288, Hh = 48, Ww = 48;
static constexpr int HW = Hh * Ww;          // 2304
static constexpr int Mtot = Bn * HW;        // 18432
static constexpr int NH = 9, HD = 32;
static constexpr int Cff = 2592;
static constexpr int CffP = 2688;           // padded: 21 x 128 (mid width)
static constexpr int NQ = 864;              // QKV cols, exact (9 x 96)

typedef __attribute__((ext_vector_type(8))) short bf16x8;
typedef __attribute__((ext_vector_type(4))) float f32x4;
typedef __attribute__((ext_vector_type(4))) unsigned short u16x4;

typedef const __attribute__((address_space(1))) unsigned gmem_word;
typedef __attribute__((address_space(3))) unsigned lds_word;

__device__ __forceinline__ void gload16(const void* g, void* l) {
    // async global->LDS, 16B per lane; LDS dest = wave-uniform base + lane*16
    __builtin_amdgcn_global_load_lds((gmem_word*)g, (lds_word*)l, 16, 0, 0);
}

template <int N>
__device__ __forceinline__ void vmwait() {
    asm volatile("s_waitcnt vmcnt(%0)" :: "n"(N) : "memory");
}

// XOR swizzle: involution on byte addresses (bits 4-6 ^= bits 7-9)
__device__ __forceinline__ int swz(int byte) {
    return byte ^ (((byte >> 7) & 7) << 4);
}

__device__ __forceinline__ float bf2f(unsigned short u) {
    return __bfloat162float(*(__hip_bfloat16*)&u);
}

__device__ __forceinline__ unsigned short f2bf(float f) {
    __hip_bfloat16 h = __float2bfloat16(f);
    return *(unsigned short*)&h;
}

// ---------------------------------------------------------------- merged prologue
// Part 1 (blocks < TBLK): x (B,C,H,W) f32 -> xlb (M,C) bf16 transpose.
// Part 2: weight repack segments:
//   wqkvt (NQ x 288) | wot (288 x 288) | w1b (CffP x 288, rows>=Cff zero) |
//   w2b (288 x CffP, cols>=Cff zero)   | b1p (CffP)
__global__ __launch_bounds__(256) void prologue(const float* __restrict__ x,
                                                __hip_bfloat16* __restrict__ xlb,
                                                const float* __restrict__ WQ,
                                                const float* __restrict__ WK,
                                                const float* __restrict__ WV,
                                                const float* __restrict__ WO,
                                                const float* __restrict__ f1w,
                                                const float* __restrict__ f2w,
                                                const float* __restrict__ f1b,
                                                __hip_bfloat16* __restrict__ wqkvt,
                                                __hip_bfloat16* __restrict__ wot,
                                                __hip_bfloat16* __restrict__ w1b,
                                                __hip_bfloat16* __restrict__ w2b,
                                                float* __restrict__ b1p) {
    constexpr int TBLK = (HW / 32) * (Cc / 32) * Bn;   // 5184
    __shared__ float tile[32][33];
    const int blk = blockIdx.x;
    if (blk < TBLK) {
        int px = blk % (HW / 32);
        int rest = blk / (HW / 32);
        int cy = rest % (Cc / 32);
        int b = rest / (Cc / 32);
        int tx = threadIdx.x & 31, ty = threadIdx.x >> 5;
        int c0 = cy * 32, p0 = px * 32;
#pragma unroll
        for (int q = 0; q < 4; ++q) {
            int c = c0 + ty + q * 8;
            tile[ty + q * 8][tx] = x[((size_t)b * Cc + c) * HW + p0 + tx];
        }
        __syncthreads();
#pragma unroll
        for (int q = 0; q < 4; ++q) {
            int p = p0 + ty + q * 8;
            xlb[((size_t)b * HW + p) * Cc + c0 + tx] = __float2bfloat16(tile[tx][ty + q * 8]);
        }
        return;
    }
    const int n1 = NQ * Cc;
    const int n2 = n1 + Cc * Cc;
    const int n3 = n2 + CffP * Cc;
    const int n4 = n3 + Cc * CffP;
    const int n5 = n4 + CffP;
    int t = (blk - TBLK) * 256 + threadIdx.x;
    if (t < n1) {
        int n = t / Cc, c = t % Cc;
        int g = n / Cc, r = n % Cc, h = r / HD, d = r % HD;
        const float* W = (g == 0) ? WQ : ((g == 1) ? WK : WV);
        wqkvt[t] = __float2bfloat16(W[((size_t)h * Cc + c) * HD + d]);
    } else if (t < n2) {
        int u = t - n1;
        int n = u / Cc, c = u % Cc;
        wot[u] = __float2bfloat16(WO[(size_t)c * Cc + n]);
    } else if (t < n3) {
        int u = t - n2;
        w1b[u] = __float2bfloat16(u < Cff * Cc ? f1w[u] : 0.f);
    } else if (t < n4) {
        int u = t - n3;
        int n = u / CffP, c = u % CffP;
        w2b[u] = __float2bfloat16(c < Cff ? f2w[(size_t)n * Cff + c] : 0.f);
    } else if (t < n5) {
        int u = t - n4;
        b1p[u] = (u < Cff) ? f1b[u] : 0.f;
    }
}

// ---------------------------------------------------------------- bf16 MFMA GEMM (BM x BN)
// C (MxN) = A (M x ldk bf16 rm) * Bw^T, Bw (N x ldk bf16 rm) [+bias][relu]
// Split-K via decoded bz (plane bz of size M*N). XCD-chunked swizzle (nwg%8==0).
// K-loop: 2-deep prefetch, counted vmcnt + raw s_barrier, setprio.
// bf16 epilogue: LDS-bounce for fully-coalesced 256B stores (aliases staging LDS).
template <int BM, int BN, bool OUT_BF16, bool BIAS, bool RELU>
__global__ __launch_bounds__(256) void gemm_mfma(const __hip_bfloat16* __restrict__ A,
                                                 const __hip_bfloat16* __restrict__ Bw,
                                                 const float* __restrict__ bias,
                                                 void* __restrict__ Cout,
                                                 int M, int N, int K, int ldk) {
    constexpr int MR = BM / 32;
    constexpr int NF = BN / 32;
    constexpr int CA = BM / 16;
    constexpr int CB = BN / 16;
    constexpr int TOT = CA + CB;                 // staging chunks per batch
    constexpr int STAGE_B = (BM + BN) * 128;     // 2 bufs x (BM+BN)*32 elems x 2B
    constexpr int TILE_B = BM * BN * 2;
    constexpr int SMEM_B = STAGE_B > TILE_B ? STAGE_B : TILE_B;
    __shared__ char smem[SMEM_B];

    const int gx = gridDim.x, gy = gridDim.y;
    const int nwg = gx * gy * gridDim.z;
    int lin = blockIdx.x + gx * (blockIdx.y + gy * blockIdx.z);
    lin = (lin & 7) * (nwg >> 3) + (lin >> 3);
    const int bz = lin / (gx * gy);
    const int rem = lin - bz * gx * gy;
    const int by = rem / gx;
    const int bx = rem - by * gx;

    const int tid = threadIdx.x;
    const int wave = tid >> 6, lane = tid & 63;
    const int l16 = lane & 15, lq = lane >> 4;
    const int wr = wave >> 1, wc = wave & 1;
    const int bm = by * BM;
    const int bn = bx * BN;
    const int nt = K >> 5;
    const size_t kz2 = (size_t)bz * K * 2;
    const char* Ab = (const char*)A + kz2;
    const char* Bb = (const char*)Bw + kz2;
    const size_t ldk2 = (size_t)ldk * 2;

    // staging region layout: A bufs at [0, 2*BM*64), B bufs at [2*BM*64, ...)
    char* const Abuf0 = smem;
    char* const Abuf1 = smem + BM * 64;
    char* const Bbuf0 = smem + 2 * BM * 64;
    char* const Bbuf1 = smem + 2 * BM * 64 + BN * 64;

    f32x4 acc[MR][NF] = {};

    auto stage = [&](int buf, int t) {
        char* Ad = buf ? Abuf1 : Abuf0;
        char* Bd = buf ? Bbuf1 : Bbuf0;
        const size_t k0b = (size_t)(t << 5) * 2;
        for (int c = wave; c < TOT; c += 4) {
            if (c < CA) {
                int s = (c << 10) + lane * 16;
                int u = swz(s);
                int row = u >> 6, koff = u & 63;
                gload16(Ab + (size_t)(bm + row) * ldk2 + k0b + koff, Ad + (c << 10));
            } else {
                int s = ((c - CA) << 10) + lane * 16;
                int u = swz(s);
                int row = u >> 6, koff = u & 63;
                gload16(Bb + (size_t)(bn + row) * ldk2 + k0b + koff, Bd + ((c - CA) << 10));
            }
        }
    };

    int aoff[MR], boff[NF];
#pragma unroll
    for (int m = 0; m < MR; ++m)
        aoff[m] = swz((wr * (BM / 2) + m * 16 + l16) * 64 + lq * 16);
#pragma unroll
    for (int n = 0; n < NF; ++n)
        boff[n] = swz((wc * (BN / 2) + n * 16 + l16) * 64 + lq * 16);

    stage(0, 0);
    stage(1, 1);                       // nt >= 9 always
    int cur = 0;
    for (int t = 0; t < nt; ++t) {
        // wait for batch t only; batch t+1 stays in flight
        if (t == nt - 1) {
            vmwait<0>();
        } else if constexpr ((TOT & 3) == 0) {
            vmwait<TOT / 4>();
        } else {
            if (wave < (TOT & 3)) vmwait<(TOT + 3) / 4>();
            else                  vmwait<TOT / 4>();
        }
        __builtin_amdgcn_s_barrier();   // buf[cur] staged for everyone
        const char* Ac = cur ? Abuf1 : Abuf0;
        const char* Bc = cur ? Bbuf1 : Bbuf0;
        bf16x8 a[MR], b[NF];
#pragma unroll
        for (int m = 0; m < MR; ++m) a[m] = *(const bf16x8*)(Ac + aoff[m]);
#pragma unroll
        for (int n = 0; n < NF; ++n) b[n] = *(const bf16x8*)(Bc + boff[n]);
        __builtin_amdgcn_s_setprio(1);
#pragma unroll
        for (int m = 0; m < MR; ++m)
#pragma unroll
            for (int n = 0; n < NF; ++n)
                acc[m][n] = __builtin_amdgcn_mfma_f32_16x16x32_bf16(a[m], b[n], acc[m][n], 0, 0, 0);
        __builtin_amdgcn_s_setprio(0);
        __builtin_amdgcn_s_barrier();   // all reads of buf[cur] done
        if (t + 2 < nt) stage(cur, t + 2);
        cur ^= 1;
    }

    const size_t plane = (size_t)bz * M * N;
    if constexpr (OUT_BF16) {
        // deposit acc (+bias/relu) into swizzled LDS out-tile (staging LDS is dead)
#pragma unroll
        for (int m = 0; m < MR; ++m) {
#pragma unroll
            for (int n = 0; n < NF; ++n) {
                const int col = wc * (BN / 2) + n * 16 + l16;
                const float bv = BIAS ? bias[bn + col] : 0.f;
#pragma unroll
                for (int r = 0; r < 4; ++r) {
                    const int row = wr * (BM / 2) + m * 16 + lq * 4 + r;
                    float v = acc[m][n][r] + bv;
                    if (RELU) v = fmaxf(v, 0.f);
                    *(__hip_bfloat16*)(smem + swz(row * (BN * 2) + col * 2)) = __float2bfloat16(v);
                }
            }
        }
        __syncthreads();
        // coalesced stream-out: 8B per thread-iter, 256B contiguous per row-chunk
        char* outp = (char*)Cout + plane * 2;
#pragma unroll
        for (int it = 0; it < TILE_B / 2048; ++it) {
            const int byte = (it * 256 + tid) * 8;
            const int row = byte / (BN * 2);
            const int off = byte - row * (BN * 2);
            u16x4 val = *(const u16x4*)(smem + swz(byte));
            *(u16x4*)(outp + ((size_t)(bm + row) * N + bn) * 2 + off) = val;
        }
    } else {
#pragma unroll
        for (int m = 0; m < MR; ++m) {
#pragma unroll
            for (int n = 0; n < NF; ++n) {
                const int col = bn + wc * (BN / 2) + n * 16 + l16;
                const float bv = BIAS ? bias[col] : 0.f;
#pragma unroll
                for (int r = 0; r < 4; ++r) {
                    const int row = bm + wr * (BM / 2) + m * 16 + lq * 4 + r;
                    float v = acc[m][n][r] + bv;
                    if (RELU) v = fmaxf(v, 0.f);
                    ((float*)Cout)[plane + (size_t)row * N + col] = v;
                }
            }
        }
    }
}

// ---------------------------------------------------------------- GEMM + fused LN epilogue (W_O + LN1 + ReLU)
// Tile 32x288 (full row), BK=32, 4 waves, wave tile 16x144, acc[9].
template <bool BIAS>
__global__ __launch_bounds__(256) void gemm_ln(const __hip_bfloat16* __restrict__ A,
                                               const __hip_bfloat16* __restrict__ Bw,
                                               const float* __restrict__ bias,
                                               const float* __restrict__ gam,
                                               const float* __restrict__ bet,
                                               __hip_bfloat16* __restrict__ dst,
                                               int K) {
    __shared__ __hip_bfloat16 As[2][32 * 32];
    __shared__ __hip_bfloat16 Bs[2][288 * 32];
    __shared__ float red[2][2][32];
    const int tid = threadIdx.x;
    const int wave = tid >> 6, lane = tid & 63;
    const int l16 = lane & 15, lq = lane >> 4;
    const int wr = wave >> 1, wc = wave & 1;
    const int bm = blockIdx.x * 32;
    const int nt = K >> 5;
    const char* Ab = (const char*)A;
    const char* Bb = (const char*)Bw;
    const size_t Ks2 = (size_t)K * 2;

    f32x4 acc[9] = {};

    auto stage = [&](int buf, int t) {
        const size_t k0b = (size_t)(t << 5) * 2;
        for (int c = wave; c < 20; c += 4) {
            if (c < 2) {
                int s = (c << 10) + lane * 16;
                int u = swz(s);
                int row = u >> 6, koff = u & 63;
                gload16(Ab + (size_t)(bm + row) * Ks2 + k0b + koff, &As[buf][c << 9]);
            } else {
                int s = ((c - 2) << 10) + lane * 16;
                int u = swz(s);
                int row = u >> 6, koff = u & 63;
                gload16(Bb + (size_t)row * Ks2 + k0b + koff, &Bs[buf][(c - 2) << 9]);
            }
        }
    };

    const int aoff = swz((wr * 16 + l16) * 64 + lq * 16);
    int boff[9];
#pragma unroll
    for (int n = 0; n < 9; ++n)
        boff[n] = swz((wc * 144 + n * 16 + l16) * 64 + lq * 16);

    stage(0, 0);
    stage(1, 1);
    int cur = 0;
    for (int t = 0; t < nt; ++t) {
        if (t == nt - 1) vmwait<0>();
        else             vmwait<5>();
        __builtin_amdgcn_s_barrier();
        const char* Ac = (const char*)&As[cur][0];
        const char* Bc = (const char*)&Bs[cur][0];
        bf16x8 a = *(const bf16x8*)(Ac + aoff);
        bf16x8 b[9];
#pragma unroll
        for (int n = 0; n < 9; ++n) b[n] = *(const bf16x8*)(Bc + boff[n]);
        __builtin_amdgcn_s_setprio(1);
#pragma unroll
        for (int n = 0; n < 9; ++n)
            acc[n] = __builtin_amdgcn_mfma_f32_16x16x32_bf16(a, b[n], acc[n], 0, 0, 0);
        __builtin_amdgcn_s_setprio(0);
        __builtin_amdgcn_s_barrier();
        if (t + 2 < nt) stage(cur, t + 2);
        cur ^= 1;
    }

    if (BIAS) {
#pragma unroll
        for (int n = 0; n < 9; ++n) {
            const float bv = bias[wc * 144 + n * 16 + l16];
#pragma unroll
            for (int r = 0; r < 4; ++r) acc[n][r] += bv;
        }
    }
    float sum[4] = {0.f, 0.f, 0.f, 0.f}, sq[4] = {0.f, 0.f, 0.f, 0.f};
#pragma unroll
    for (int n = 0; n < 9; ++n)
#pragma unroll
        for (int r = 0; r < 4; ++r) { sum[r] += acc[n][r]; sq[r] += acc[n][r] * acc[n][r]; }
#pragma unroll
    for (int s = 8; s >= 1; s >>= 1) {
#pragma unroll
        for (int r = 0; r < 4; ++r) { sum[r] += __shfl_xor(sum[r], s); sq[r] += __shfl_xor(sq[r], s); }
    }
    if (l16 == 0) {
#pragma unroll
        for (int r = 0; r < 4; ++r) {
            red[0][wc][wr * 16 + lq * 4 + r] = sum[r];
            red[1][wc][wr * 16 + lq * 4 + r] = sq[r];
        }
    }
    __syncthreads();
    float mean[4], rstd[4];
#pragma unroll
    for (int r = 0; r < 4; ++r) {
        const int rl = wr * 16 + lq * 4 + r;
        const float S = red[0][0][rl] + red[0][1][rl];
        const float Q = red[1][0][rl] + red[1][1][rl];
        mean[r] = S * (1.f / Cc);
        rstd[r] = rsqrtf(Q * (1.f / Cc) - mean[r] * mean[r] + 1e-5f);
    }
#pragma unroll
    for (int n = 0; n < 9; ++n) {
        const int col = wc * 144 + n * 16 + l16;
        const float gm = gam[col], bt = bet[col];
#pragma unroll
        for (int r = 0; r < 4; ++r) {
            const int row = bm + wr * 16 + lq * 4 + r;
            float y = (acc[n][r] - mean[r]) * rstd[r] * gm + bt;
            dst[(size_t)row * Cc + col] = __float2bfloat16(fmaxf(y, 0.f));
        }
    }
}

// ---------------------------------------------------------------- attention (qkv stride NQ=864, vectorized x4)
// 8 lanes per (pixel, head); each lane owns 4 consecutive d's (u16x4 loads).
// Grid covers ALL pixels; border pixels write zeros (replaces the memset).
__global__ __launch_bounds__(256) void attn_kernel(const __hip_bfloat16* __restrict__ qkv,
                                                   __hip_bfloat16* __restrict__ aout) {
    int t = blockIdx.x * 256 + threadIdx.x;
    int l8 = t & 7;
    int ph = t >> 3;           // (pixel, head): Mtot * 9 total, exact grid
    int h = ph % 9;
    int m = ph / 9;            // global pixel index = b*HW + p
    int p = m % HW;
    int i = p / Ww, j = p % Ww;
    int hd = h * HD + l8 * 4;
    unsigned short* op = (unsigned short*)aout + (size_t)m * Cc + hd;
    if (i == 0 || i == Hh - 1 || j == 0 || j == Ww - 1) {
        u16x4 z = {0, 0, 0, 0};
        *(u16x4*)op = z;
        return;
    }
    const unsigned short* qp = (const unsigned short*)qkv;
    u16x4 qv = *(const u16x4*)(qp + (size_t)m * NQ + hd);
    float q0 = bf2f(qv[0]), q1 = bf2f(qv[1]), q2 = bf2f(qv[2]), q3 = bf2f(qv[3]);
    float logits[9];
    int mns[9];
#pragma unroll
    for (int n = 0; n < 9; ++n) {
        int di = n / 3, dj = n % 3;
        int mn = m + (di - 1) * Ww + (dj - 1);
        mns[n] = mn;
        u16x4 kv = *(const u16x4*)(qp + (size_t)mn * NQ + 288 + hd);
        float pl = q0 * bf2f(kv[0]) + q1 * bf2f(kv[1]) + q2 * bf2f(kv[2]) + q3 * bf2f(kv[3]);
        pl += __shfl_xor(pl, 1);
        pl += __shfl_xor(pl, 2);
        pl += __shfl_xor(pl, 4);
        logits[n] = pl * 0.17677669529663687f;   // 1/sqrt(32)
    }
    float mx = logits[0];
#pragma unroll
    for (int n = 1; n < 9; ++n) mx = fmaxf(mx, logits[n]);
    float w[9];
    float sum = 0.f;
#pragma unroll
    for (int n = 0; n < 9; ++n) { w[n] = expf(logits[n] - mx); sum += w[n]; }
    float inv = 1.f / sum;
    float o0 = 0.f, o1 = 0.f, o2 = 0.f, o3 = 0.f;
#pragma unroll
    for (int n = 0; n < 9; ++n) {
        u16x4 vv = *(const u16x4*)(qp + (size_t)mns[n] * NQ + 576 + hd);
        o0 += w[n] * bf2f(vv[0]);
        o1 += w[n] * bf2f(vv[1]);
        o2 += w[n] * bf2f(vv[2]);
        o3 += w[n] * bf2f(vv[3]);
    }
    u16x4 ov;
    ov[0] = f2bf(o0 * inv); ov[1] = f2bf(o1 * inv);
    ov[2] = f2bf(o2 * inv); ov[3] = f2bf(o3 * inv);
    *(u16x4*)op = ov;
}

// ---------------------------------------------------------------- final: 3 bf16-plane reduce + b2 + LN2 + residual + relu + COALESCED transpose out
__global__ __launch_bounds__(256) void final_kernel(const __hip_bfloat16* __restrict__ part,
                                                    const float* __restrict__ fb2,
                                                    const __hip_bfloat16* __restrict__ xlb,
                                                    const float* __restrict__ g,
                                                    const float* __restrict__ bta,
                                                    float* __restrict__ out) {
    __shared__ float T[32][289];
    const int tid = threadIdx.x;
    const int wave = tid >> 6, lane = tid & 63;
    const int p0 = blockIdx.x * 32;          // global pixel base (HW=2304 -> same b)
    const int b = p0 / HW;
    const int p = p0 % HW;
    const size_t plane = (size_t)Mtot * Cc;
    const unsigned short* pt = (const unsigned short*)part;
    const unsigned short* xr = (const unsigned short*)xlb;

    for (int it = 0; it < 8; ++it) {
        const int pw = wave * 8 + it;
        const size_t base = (size_t)(p0 + pw) * Cc;
        const int c0 = lane * 4;
        const int c1 = 256 + lane * 4;       // valid for lane < 8
        float v0[4], v1[4];
        {
            u16x4 a = *(const u16x4*)(pt + base + c0);
            u16x4 bb = *(const u16x4*)(pt + plane + base + c0);
            u16x4 cc = *(const u16x4*)(pt + 2 * plane + base + c0);
#pragma unroll
            for (int j = 0; j < 4; ++j)
                v0[j] = bf2f(a[j]) + bf2f(bb[j]) + bf2f(cc[j]) + fb2[c0 + j];
        }
        if (lane < 8) {
            u16x4 a = *(const u16x4*)(pt + base + c1);
            u16x4 bb = *(const u16x4*)(pt + plane + base + c1);
            u16x4 cc = *(const u16x4*)(pt + 2 * plane + base + c1);
#pragma unroll
            for (int j = 0; j < 4; ++j)
                v1[j] = bf2f(a[j]) + bf2f(bb[j]) + bf2f(cc[j]) + fb2[c1 + j];
        } else {
#pragma unroll
            for (int j = 0; j < 4; ++j) v1[j] = 0.f;
        }
        float sum = 0.f, sq = 0.f;
#pragma unroll
        for (int j = 0; j < 4; ++j) {
            sum += v0[j] + v1[j];
            sq += v0[j] * v0[j] + v1[j] * v1[j];
        }
#pragma unroll
        for (int s = 32; s >= 1; s >>= 1) { sum += __shfl_xor(sum, s); sq += __shfl_xor(sq, s); }
        const float mean = sum * (1.f / Cc);
        const float rstd = rsqrtf(sq * (1.f / Cc) - mean * mean + 1e-5f);
        {
            u16x4 xv = *(const u16x4*)(xr + base + c0);
#pragma unroll
            for (int j = 0; j < 4; ++j) {
                float y = (v0[j] - mean) * rstd * g[c0 + j] + bta[c0 + j];
                T[pw][c0 + j] = fmaxf(y + bf2f(xv[j]), 0.f);
            }
        }
        if (lane < 8) {
            u16x4 xv = *(const u16x4*)(xr + base + c1);
#pragma unroll
            for (int j = 0; j < 4; ++j) {
                float y = (v1[j] - mean) * rstd * g[c1 + j] + bta[c1 + j];
                T[pw][c1 + j] = fmaxf(y + bf2f(xv[j]), 0.f);
            }
        }
    }
    __syncthreads();
#pragma unroll
    for (int k = 0; k < 36; ++k) {
        const int idx = k * 256 + tid;
        const int c = idx >> 5, pw = idx & 31;
        out[((size_t)b * Cc + c) * HW + p + pw] = T[pw][c];
    }
}

// ---------------------------------------------------------------- ws-too-small sentinel
__global__ void sentinel_kernel(float* out, float val) {
    out[threadIdx.x] = val;
}

extern "C" void kernel_launch(void* const* d_in, const int* in_sizes, int n_in,
                              void* d_out, int out_size, void* d_ws, size_t ws_size,
                              hipStream_t stream) {
    const float* x   = (const float*)d_in[0];
    const float* WQ  = (const float*)d_in[1];
    const float* WK  = (const float*)d_in[2];
    const float* WV  = (const float*)d_in[3];
    const float* WO  = (const float*)d_in[4];
    const float* f1w = (const float*)d_in[5];
    const float* f1b = (const float*)d_in[6];
    const float* f2w = (const float*)d_in[7];
    const float* f2b = (const float*)d_in[8];
    const float* g1  = (const float*)d_in[9];
    const float* b1  = (const float*)d_in[10];
    const float* g2  = (const float*)d_in[11];
    const float* b2  = (const float*)d_in[12];

    char* ws = (char*)d_ws;
    size_t off = 0;
    auto alloc = [&](size_t bytes) { void* p = ws + off; off += (bytes + 255) & ~(size_t)255; return p; };

    __hip_bfloat16* xlb   = (__hip_bfloat16*)alloc((size_t)Mtot * Cc * 2);
    __hip_bfloat16* wqkvt = (__hip_bfloat16*)alloc((size_t)NQ * Cc * 2);
    __hip_bfloat16* qkv   = (__hip_bfloat16*)alloc((size_t)Mtot * NQ * 2);
    __hip_bfloat16* aout  = (__hip_bfloat16*)alloc((size_t)Mtot * Cc * 2);
    __hip_bfloat16* wot   = (__hip_bfloat16*)alloc((size_t)Cc * Cc * 2);
    __hip_bfloat16* yln   = (__hip_bfloat16*)alloc((size_t)Mtot * Cc * 2);
    __hip_bfloat16* w1b   = (__hip_bfloat16*)alloc((size_t)CffP * Cc * 2);
    float*          b1p   = (float*)alloc((size_t)CffP * 4);
    __hip_bfloat16* mid   = (__hip_bfloat16*)alloc((size_t)Mtot * CffP * 2);
    __hip_bfloat16* w2b   = (__hip_bfloat16*)alloc((size_t)Cc * CffP * 2);
    __hip_bfloat16* f2o3  = (__hip_bfloat16*)alloc((size_t)3 * Mtot * Cc * 2);

    if (ws_size < off) {
        sentinel_kernel<<<1, 256, 0, stream>>>((float*)d_out, (float)off * 1e-6f);
        return;
    }

    // merged transpose + weight prep (one dispatch)
    {
        constexpr int TBLK = (HW / 32) * (Cc / 32) * Bn;   // 5184
        const int prep_total = NQ * Cc + Cc * Cc + CffP * Cc + Cc * CffP + CffP;
        const int grid = TBLK + (prep_total + 255) / 256;
        prologue<<<grid, 256, 0, stream>>>(
            x, xlb, WQ, WK, WV, WO, f1w, f2w, f1b, wqkvt, wot, w1b, w2b, b1p);
    }

    // QKV: (M x 288) * (288 x 864) -> bf16, 96x96 tiles (grid 1728 = 6.75/CU)
    gemm_mfma<96, 96, true, false, false><<<dim3(NQ / 96, Mtot / 96, 1), 256, 0, stream>>>(
        xlb, wqkvt, nullptr, qkv, Mtot, NQ, Cc, Cc);

    // attention over ALL pixels (border pixels write zeros; replaces memset)
    attn_kernel<<<(Mtot * 9 * 8) / 256, 256, 0, stream>>>(qkv, aout);

    // W_O + LN1 + ReLU fused: yln = bf16(relu(LN(aout * WO)))
    gemm_ln<false><<<Mtot / 32, 256, 0, stream>>>(
        aout, wot, nullptr, g1, b1, yln, Cc);

    // FFN1: (M x 288) * (288 x 2688) + b1, relu -> bf16 (grid 3024)
    gemm_mfma<128, 128, true, true, true><<<dim3(CffP / 128, Mtot / 128, 1), 256, 0, stream>>>(
        yln, w1b, b1p, mid, Mtot, CffP, Cc, Cc);

    // FFN2: (M x 2688) * (2688 x 288) -> 3 bf16 partial planes, split-K (grid 1728)
    gemm_mfma<96, 96, true, false, false><<<dim3(Cc / 96, Mtot / 96, 3), 256, 0, stream>>>(
        mid, w2b, nullptr, f2o3, Mtot, Cc, CffP / 3, CffP);

    // 3-plane reduce + b2 + LN2 + residual + ReLU + coalesced transpose out
    final_kernel<<<Mtot / 32, 256, 0, stream>>>(f2o3, f2b, xlb, g2, b2, (float*)d_out);
}

// Round 16
// 185.756 us; speedup vs baseline: 1.0983x; 1.0983x over previous
//
#include <hip/hip_runtime.h>
#include <hip/hip_bf16.h>

static constexpr int Bn = 8, Cc = 288, Hh = 48, Ww = 48;
static constexpr int HW = Hh * Ww;          // 2304
static constexpr int Mtot = Bn * HW;        // 18432
static constexpr int NH = 9, HD = 32;
static constexpr int Cff = 2592;
static constexpr int CffP = 2688;           // padded: 21 x 128 (mid width)
static constexpr int NQ = 864;              // QKV cols, exact (9 x 96)

typedef __attribute__((ext_vector_type(8))) short bf16x8;
typedef __attribute__((ext_vector_type(4))) float f32x4;
typedef __attribute__((ext_vector_type(4))) unsigned short u16x4;

typedef const __attribute__((address_space(1))) unsigned gmem_word;
typedef __attribute__((address_space(3))) unsigned lds_word;

__device__ __forceinline__ void gload16(const void* g, void* l) {
    // async global->LDS, 16B per lane; LDS dest = wave-uniform base + lane*16
    __builtin_amdgcn_global_load_lds((gmem_word*)g, (lds_word*)l, 16, 0, 0);
}

template <int N>
__device__ __forceinline__ void vmwait() {
    asm volatile("s_waitcnt vmcnt(%0)" :: "n"(N) : "memory");
}

// XOR swizzle: involution on byte addresses (bits 4-6 ^= bits 7-9)
__device__ __forceinline__ int swz(int byte) {
    return byte ^ (((byte >> 7) & 7) << 4);
}

__device__ __forceinline__ float bf2f(unsigned short u) {
    return __bfloat162float(*(__hip_bfloat16*)&u);
}

__device__ __forceinline__ unsigned short f2bf(float f) {
    __hip_bfloat16 h = __float2bfloat16(f);
    return *(unsigned short*)&h;
}

// ---------------------------------------------------------------- merged prologue
// Part 1 (blocks < TBLK): x (B,C,H,W) f32 -> xlb (M,C) bf16 transpose.
// Part 2: weight repack segments:
//   wqkvt (NQ x 288) | wot (288 x 288) | w1b (CffP x 288, rows>=Cff zero) |
//   w2b (288 x CffP, cols>=Cff zero)   | b1p (CffP)
__global__ __launch_bounds__(256) void prologue(const float* __restrict__ x,
                                                __hip_bfloat16* __restrict__ xlb,
                                                const float* __restrict__ WQ,
                                                const float* __restrict__ WK,
                                                const float* __restrict__ WV,
                                                const float* __restrict__ WO,
                                                const float* __restrict__ f1w,
                                                const float* __restrict__ f2w,
                                                const float* __restrict__ f1b,
                                                __hip_bfloat16* __restrict__ wqkvt,
                                                __hip_bfloat16* __restrict__ wot,
                                                __hip_bfloat16* __restrict__ w1b,
                                                __hip_bfloat16* __restrict__ w2b,
                                                float* __restrict__ b1p) {
    constexpr int TBLK = (HW / 32) * (Cc / 32) * Bn;   // 5184
    __shared__ float tile[32][33];
    const int blk = blockIdx.x;
    if (blk < TBLK) {
        int px = blk % (HW / 32);
        int rest = blk / (HW / 32);
        int cy = rest % (Cc / 32);
        int b = rest / (Cc / 32);
        int tx = threadIdx.x & 31, ty = threadIdx.x >> 5;
        int c0 = cy * 32, p0 = px * 32;
#pragma unroll
        for (int q = 0; q < 4; ++q) {
            int c = c0 + ty + q * 8;
            tile[ty + q * 8][tx] = x[((size_t)b * Cc + c) * HW + p0 + tx];
        }
        __syncthreads();
#pragma unroll
        for (int q = 0; q < 4; ++q) {
            int p = p0 + ty + q * 8;
            xlb[((size_t)b * HW + p) * Cc + c0 + tx] = __float2bfloat16(tile[tx][ty + q * 8]);
        }
        return;
    }
    const int n1 = NQ * Cc;
    const int n2 = n1 + Cc * Cc;
    const int n3 = n2 + CffP * Cc;
    const int n4 = n3 + Cc * CffP;
    const int n5 = n4 + CffP;
    int t = (blk - TBLK) * 256 + threadIdx.x;
    if (t < n1) {
        int n = t / Cc, c = t % Cc;
        int g = n / Cc, r = n % Cc, h = r / HD, d = r % HD;
        const float* W = (g == 0) ? WQ : ((g == 1) ? WK : WV);
        wqkvt[t] = __float2bfloat16(W[((size_t)h * Cc + c) * HD + d]);
    } else if (t < n2) {
        int u = t - n1;
        int n = u / Cc, c = u % Cc;
        wot[u] = __float2bfloat16(WO[(size_t)c * Cc + n]);
    } else if (t < n3) {
        int u = t - n2;
        w1b[u] = __float2bfloat16(u < Cff * Cc ? f1w[u] : 0.f);
    } else if (t < n4) {
        int u = t - n3;
        int n = u / CffP, c = u % CffP;
        w2b[u] = __float2bfloat16(c < Cff ? f2w[(size_t)n * Cff + c] : 0.f);
    } else if (t < n5) {
        int u = t - n4;
        b1p[u] = (u < Cff) ? f1b[u] : 0.f;
    }
}

// ---------------------------------------------------------------- bf16 MFMA GEMM (BM x BN)
// C (MxN) = A (M x ldk bf16 rm) * Bw^T, Bw (N x ldk bf16 rm) [+bias][relu]
// Split-K via decoded bz (plane bz of size M*N). XCD-chunked swizzle (nwg%8==0).
// K-loop: 2-deep prefetch, counted vmcnt + raw s_barrier, setprio.
template <int BM, int BN, bool OUT_BF16, bool BIAS, bool RELU>
__global__ __launch_bounds__(256) void gemm_mfma(const __hip_bfloat16* __restrict__ A,
                                                 const __hip_bfloat16* __restrict__ Bw,
                                                 const float* __restrict__ bias,
                                                 void* __restrict__ Cout,
                                                 int M, int N, int K, int ldk) {
    constexpr int MR = BM / 32;
    constexpr int NF = BN / 32;
    constexpr int CA = BM / 16;
    constexpr int CB = BN / 16;
    constexpr int TOT = CA + CB;       // staging chunks per batch
    __shared__ __hip_bfloat16 As[2][BM * 32];
    __shared__ __hip_bfloat16 Bs[2][BN * 32];
    const int gx = gridDim.x, gy = gridDim.y;
    const int nwg = gx * gy * gridDim.z;
    int lin = blockIdx.x + gx * (blockIdx.y + gy * blockIdx.z);
    lin = (lin & 7) * (nwg >> 3) + (lin >> 3);
    const int bz = lin / (gx * gy);
    const int rem = lin - bz * gx * gy;
    const int by = rem / gx;
    const int bx = rem - by * gx;

    const int tid = threadIdx.x;
    const int wave = tid >> 6, lane = tid & 63;
    const int l16 = lane & 15, lq = lane >> 4;
    const int wr = wave >> 1, wc = wave & 1;
    const int bm = by * BM;
    const int bn = bx * BN;
    const int nt = K >> 5;
    const size_t kz2 = (size_t)bz * K * 2;
    const char* Ab = (const char*)A + kz2;
    const char* Bb = (const char*)Bw + kz2;
    const size_t ldk2 = (size_t)ldk * 2;

    f32x4 acc[MR][NF] = {};

    auto stage = [&](int buf, int t) {
        const size_t k0b = (size_t)(t << 5) * 2;
        for (int c = wave; c < TOT; c += 4) {
            if (c < CA) {
                int s = (c << 10) + lane * 16;
                int u = swz(s);
                int row = u >> 6, koff = u & 63;
                gload16(Ab + (size_t)(bm + row) * ldk2 + k0b + koff, &As[buf][c << 9]);
            } else {
                int s = ((c - CA) << 10) + lane * 16;
                int u = swz(s);
                int row = u >> 6, koff = u & 63;
                gload16(Bb + (size_t)(bn + row) * ldk2 + k0b + koff, &Bs[buf][(c - CA) << 9]);
            }
        }
    };

    int aoff[MR], boff[NF];
#pragma unroll
    for (int m = 0; m < MR; ++m)
        aoff[m] = swz((wr * (BM / 2) + m * 16 + l16) * 64 + lq * 16);
#pragma unroll
    for (int n = 0; n < NF; ++n)
        boff[n] = swz((wc * (BN / 2) + n * 16 + l16) * 64 + lq * 16);

    stage(0, 0);
    stage(1, 1);                       // nt >= 9 always
    int cur = 0;
    for (int t = 0; t < nt; ++t) {
        // wait for batch t only; batch t+1 stays in flight
        if (t == nt - 1) {
            vmwait<0>();
        } else if constexpr ((TOT & 3) == 0) {
            vmwait<TOT / 4>();
        } else {
            if (wave < (TOT & 3)) vmwait<(TOT + 3) / 4>();
            else                  vmwait<TOT / 4>();
        }
        __builtin_amdgcn_s_barrier();   // buf[cur] staged for everyone
        const char* Ac = (const char*)&As[cur][0];
        const char* Bc = (const char*)&Bs[cur][0];
        bf16x8 a[MR], b[NF];
#pragma unroll
        for (int m = 0; m < MR; ++m) a[m] = *(const bf16x8*)(Ac + aoff[m]);
#pragma unroll
        for (int n = 0; n < NF; ++n) b[n] = *(const bf16x8*)(Bc + boff[n]);
        __builtin_amdgcn_s_setprio(1);
#pragma unroll
        for (int m = 0; m < MR; ++m)
#pragma unroll
            for (int n = 0; n < NF; ++n)
                acc[m][n] = __builtin_amdgcn_mfma_f32_16x16x32_bf16(a[m], b[n], acc[m][n], 0, 0, 0);
        __builtin_amdgcn_s_setprio(0);
        __builtin_amdgcn_s_barrier();   // all reads of buf[cur] done
        if (t + 2 < nt) stage(cur, t + 2);
        cur ^= 1;
    }

    const size_t plane = (size_t)bz * M * N;
#pragma unroll
    for (int m = 0; m < MR; ++m) {
#pragma unroll
        for (int n = 0; n < NF; ++n) {
            const int col = bn + wc * (BN / 2) + n * 16 + l16;
            const float bv = BIAS ? bias[col] : 0.f;
#pragma unroll
            for (int r = 0; r < 4; ++r) {
                const int row = bm + wr * (BM / 2) + m * 16 + lq * 4 + r;
                float v = acc[m][n][r] + bv;
                if (RELU) v = fmaxf(v, 0.f);
                if (OUT_BF16)
                    ((__hip_bfloat16*)Cout)[plane + (size_t)row * N + col] = __float2bfloat16(v);
                else
                    ((float*)Cout)[plane + (size_t)row * N + col] = v;
            }
        }
    }
}

// ---------------------------------------------------------------- GEMM + fused LN epilogue (W_O + LN1 + ReLU)
// Tile 32x288 (full row), BK=32, 4 waves, wave tile 16x144, acc[9].
template <bool BIAS>
__global__ __launch_bounds__(256) void gemm_ln(const __hip_bfloat16* __restrict__ A,
                                               const __hip_bfloat16* __restrict__ Bw,
                                               const float* __restrict__ bias,
                                               const float* __restrict__ gam,
                                               const float* __restrict__ bet,
                                               __hip_bfloat16* __restrict__ dst,
                                               int K) {
    __shared__ __hip_bfloat16 As[2][32 * 32];
    __shared__ __hip_bfloat16 Bs[2][288 * 32];
    __shared__ float red[2][2][32];
    const int tid = threadIdx.x;
    const int wave = tid >> 6, lane = tid & 63;
    const int l16 = lane & 15, lq = lane >> 4;
    const int wr = wave >> 1, wc = wave & 1;
    const int bm = blockIdx.x * 32;
    const int nt = K >> 5;
    const char* Ab = (const char*)A;
    const char* Bb = (const char*)Bw;
    const size_t Ks2 = (size_t)K * 2;

    f32x4 acc[9] = {};

    auto stage = [&](int buf, int t) {
        const size_t k0b = (size_t)(t << 5) * 2;
        for (int c = wave; c < 20; c += 4) {
            if (c < 2) {
                int s = (c << 10) + lane * 16;
                int u = swz(s);
                int row = u >> 6, koff = u & 63;
                gload16(Ab + (size_t)(bm + row) * Ks2 + k0b + koff, &As[buf][c << 9]);
            } else {
                int s = ((c - 2) << 10) + lane * 16;
                int u = swz(s);
                int row = u >> 6, koff = u & 63;
                gload16(Bb + (size_t)row * Ks2 + k0b + koff, &Bs[buf][(c - 2) << 9]);
            }
        }
    };

    const int aoff = swz((wr * 16 + l16) * 64 + lq * 16);
    int boff[9];
#pragma unroll
    for (int n = 0; n < 9; ++n)
        boff[n] = swz((wc * 144 + n * 16 + l16) * 64 + lq * 16);

    stage(0, 0);
    stage(1, 1);
    int cur = 0;
    for (int t = 0; t < nt; ++t) {
        if (t == nt - 1) vmwait<0>();
        else             vmwait<5>();
        __builtin_amdgcn_s_barrier();
        const char* Ac = (const char*)&As[cur][0];
        const char* Bc = (const char*)&Bs[cur][0];
        bf16x8 a = *(const bf16x8*)(Ac + aoff);
        bf16x8 b[9];
#pragma unroll
        for (int n = 0; n < 9; ++n) b[n] = *(const bf16x8*)(Bc + boff[n]);
        __builtin_amdgcn_s_setprio(1);
#pragma unroll
        for (int n = 0; n < 9; ++n)
            acc[n] = __builtin_amdgcn_mfma_f32_16x16x32_bf16(a, b[n], acc[n], 0, 0, 0);
        __builtin_amdgcn_s_setprio(0);
        __builtin_amdgcn_s_barrier();
        if (t + 2 < nt) stage(cur, t + 2);
        cur ^= 1;
    }

    if (BIAS) {
#pragma unroll
        for (int n = 0; n < 9; ++n) {
            const float bv = bias[wc * 144 + n * 16 + l16];
#pragma unroll
            for (int r = 0; r < 4; ++r) acc[n][r] += bv;
        }
    }
    float sum[4] = {0.f, 0.f, 0.f, 0.f}, sq[4] = {0.f, 0.f, 0.f, 0.f};
#pragma unroll
    for (int n = 0; n < 9; ++n)
#pragma unroll
        for (int r = 0; r < 4; ++r) { sum[r] += acc[n][r]; sq[r] += acc[n][r] * acc[n][r]; }
#pragma unroll
    for (int s = 8; s >= 1; s >>= 1) {
#pragma unroll
        for (int r = 0; r < 4; ++r) { sum[r] += __shfl_xor(sum[r], s); sq[r] += __shfl_xor(sq[r], s); }
    }
    if (l16 == 0) {
#pragma unroll
        for (int r = 0; r < 4; ++r) {
            red[0][wc][wr * 16 + lq * 4 + r] = sum[r];
            red[1][wc][wr * 16 + lq * 4 + r] = sq[r];
        }
    }
    __syncthreads();
    float mean[4], rstd[4];
#pragma unroll
    for (int r = 0; r < 4; ++r) {
        const int rl = wr * 16 + lq * 4 + r;
        const float S = red[0][0][rl] + red[0][1][rl];
        const float Q = red[1][0][rl] + red[1][1][rl];
        mean[r] = S * (1.f / Cc);
        rstd[r] = rsqrtf(Q * (1.f / Cc) - mean[r] * mean[r] + 1e-5f);
    }
#pragma unroll
    for (int n = 0; n < 9; ++n) {
        const int col = wc * 144 + n * 16 + l16;
        const float gm = gam[col], bt = bet[col];
#pragma unroll
        for (int r = 0; r < 4; ++r) {
            const int row = bm + wr * 16 + lq * 4 + r;
            float y = (acc[n][r] - mean[r]) * rstd[r] * gm + bt;
            dst[(size_t)row * Cc + col] = __float2bfloat16(fmaxf(y, 0.f));
        }
    }
}

// ---------------------------------------------------------------- attention (qkv stride NQ=864, vectorized x4)
// 8 lanes per (pixel, head); each lane owns 4 consecutive d's (u16x4 loads).
// Grid covers ALL pixels; border pixels write zeros (replaces the memset).
__global__ __launch_bounds__(256) void attn_kernel(const __hip_bfloat16* __restrict__ qkv,
                                                   __hip_bfloat16* __restrict__ aout) {
    int t = blockIdx.x * 256 + threadIdx.x;
    int l8 = t & 7;
    int ph = t >> 3;           // (pixel, head): Mtot * 9 total, exact grid
    int h = ph % 9;
    int m = ph / 9;            // global pixel index = b*HW + p
    int p = m % HW;
    int i = p / Ww, j = p % Ww;
    int hd = h * HD + l8 * 4;
    unsigned short* op = (unsigned short*)aout + (size_t)m * Cc + hd;
    if (i == 0 || i == Hh - 1 || j == 0 || j == Ww - 1) {
        u16x4 z = {0, 0, 0, 0};
        *(u16x4*)op = z;
        return;
    }
    const unsigned short* qp = (const unsigned short*)qkv;
    u16x4 qv = *(const u16x4*)(qp + (size_t)m * NQ + hd);
    float q0 = bf2f(qv[0]), q1 = bf2f(qv[1]), q2 = bf2f(qv[2]), q3 = bf2f(qv[3]);
    float logits[9];
    int mns[9];
#pragma unroll
    for (int n = 0; n < 9; ++n) {
        int di = n / 3, dj = n % 3;
        int mn = m + (di - 1) * Ww + (dj - 1);
        mns[n] = mn;
        u16x4 kv = *(const u16x4*)(qp + (size_t)mn * NQ + 288 + hd);
        float pl = q0 * bf2f(kv[0]) + q1 * bf2f(kv[1]) + q2 * bf2f(kv[2]) + q3 * bf2f(kv[3]);
        pl += __shfl_xor(pl, 1);
        pl += __shfl_xor(pl, 2);
        pl += __shfl_xor(pl, 4);
        logits[n] = pl * 0.17677669529663687f;   // 1/sqrt(32)
    }
    float mx = logits[0];
#pragma unroll
    for (int n = 1; n < 9; ++n) mx = fmaxf(mx, logits[n]);
    float w[9];
    float sum = 0.f;
#pragma unroll
    for (int n = 0; n < 9; ++n) { w[n] = expf(logits[n] - mx); sum += w[n]; }
    float inv = 1.f / sum;
    float o0 = 0.f, o1 = 0.f, o2 = 0.f, o3 = 0.f;
#pragma unroll
    for (int n = 0; n < 9; ++n) {
        u16x4 vv = *(const u16x4*)(qp + (size_t)mns[n] * NQ + 576 + hd);
        o0 += w[n] * bf2f(vv[0]);
        o1 += w[n] * bf2f(vv[1]);
        o2 += w[n] * bf2f(vv[2]);
        o3 += w[n] * bf2f(vv[3]);
    }
    u16x4 ov;
    ov[0] = f2bf(o0 * inv); ov[1] = f2bf(o1 * inv);
    ov[2] = f2bf(o2 * inv); ov[3] = f2bf(o3 * inv);
    *(u16x4*)op = ov;
}

// ---------------------------------------------------------------- final: 3 bf16-plane reduce + b2 + LN2 + residual + relu + COALESCED transpose out
__global__ __launch_bounds__(256) void final_kernel(const __hip_bfloat16* __restrict__ part,
                                                    const float* __restrict__ fb2,
                                                    const __hip_bfloat16* __restrict__ xlb,
                                                    const float* __restrict__ g,
                                                    const float* __restrict__ bta,
                                                    float* __restrict__ out) {
    __shared__ float T[32][289];
    const int tid = threadIdx.x;
    const int wave = tid >> 6, lane = tid & 63;
    const int p0 = blockIdx.x * 32;          // global pixel base (HW=2304 -> same b)
    const int b = p0 / HW;
    const int p = p0 % HW;
    const size_t plane = (size_t)Mtot * Cc;
    const unsigned short* pt = (const unsigned short*)part;
    const unsigned short* xr = (const unsigned short*)xlb;

    for (int it = 0; it < 8; ++it) {
        const int pw = wave * 8 + it;
        const size_t base = (size_t)(p0 + pw) * Cc;
        const int c0 = lane * 4;
        const int c1 = 256 + lane * 4;       // valid for lane < 8
        float v0[4], v1[4];
        {
            u16x4 a = *(const u16x4*)(pt + base + c0);
            u16x4 bb = *(const u16x4*)(pt + plane + base + c0);
            u16x4 cc = *(const u16x4*)(pt + 2 * plane + base + c0);
#pragma unroll
            for (int j = 0; j < 4; ++j)
                v0[j] = bf2f(a[j]) + bf2f(bb[j]) + bf2f(cc[j]) + fb2[c0 + j];
        }
        if (lane < 8) {
            u16x4 a = *(const u16x4*)(pt + base + c1);
            u16x4 bb = *(const u16x4*)(pt + plane + base + c1);
            u16x4 cc = *(const u16x4*)(pt + 2 * plane + base + c1);
#pragma unroll
            for (int j = 0; j < 4; ++j)
                v1[j] = bf2f(a[j]) + bf2f(bb[j]) + bf2f(cc[j]) + fb2[c1 + j];
        } else {
#pragma unroll
            for (int j = 0; j < 4; ++j) v1[j] = 0.f;
        }
        float sum = 0.f, sq = 0.f;
#pragma unroll
        for (int j = 0; j < 4; ++j) {
            sum += v0[j] + v1[j];
            sq += v0[j] * v0[j] + v1[j] * v1[j];
        }
#pragma unroll
        for (int s = 32; s >= 1; s >>= 1) { sum += __shfl_xor(sum, s); sq += __shfl_xor(sq, s); }
        const float mean = sum * (1.f / Cc);
        const float rstd = rsqrtf(sq * (1.f / Cc) - mean * mean + 1e-5f);
        {
            u16x4 xv = *(const u16x4*)(xr + base + c0);
#pragma unroll
            for (int j = 0; j < 4; ++j) {
                float y = (v0[j] - mean) * rstd * g[c0 + j] + bta[c0 + j];
                T[pw][c0 + j] = fmaxf(y + bf2f(xv[j]), 0.f);
            }
        }
        if (lane < 8) {
            u16x4 xv = *(const u16x4*)(xr + base + c1);
#pragma unroll
            for (int j = 0; j < 4; ++j) {
                float y = (v1[j] - mean) * rstd * g[c1 + j] + bta[c1 + j];
                T[pw][c1 + j] = fmaxf(y + bf2f(xv[j]), 0.f);
            }
        }
    }
    __syncthreads();
#pragma unroll
    for (int k = 0; k < 36; ++k) {
        const int idx = k * 256 + tid;
        const int c = idx >> 5, pw = idx & 31;
        out[((size_t)b * Cc + c) * HW + p + pw] = T[pw][c];
    }
}

// ---------------------------------------------------------------- ws-too-small sentinel
__global__ void sentinel_kernel(float* out, float val) {
    out[threadIdx.x] = val;
}

extern "C" void kernel_launch(void* const* d_in, const int* in_sizes, int n_in,
                              void* d_out, int out_size, void* d_ws, size_t ws_size,
                              hipStream_t stream) {
    const float* x   = (const float*)d_in[0];
    const float* WQ  = (const float*)d_in[1];
    const float* WK  = (const float*)d_in[2];
    const float* WV  = (const float*)d_in[3];
    const float* WO  = (const float*)d_in[4];
    const float* f1w = (const float*)d_in[5];
    const float* f1b = (const float*)d_in[6];
    const float* f2w = (const float*)d_in[7];
    const float* f2b = (const float*)d_in[8];
    const float* g1  = (const float*)d_in[9];
    const float* b1  = (const float*)d_in[10];
    const float* g2  = (const float*)d_in[11];
    const float* b2  = (const float*)d_in[12];

    char* ws = (char*)d_ws;
    size_t off = 0;
    auto alloc = [&](size_t bytes) { void* p = ws + off; off += (bytes + 255) & ~(size_t)255; return p; };

    __hip_bfloat16* xlb   = (__hip_bfloat16*)alloc((size_t)Mtot * Cc * 2);
    __hip_bfloat16* wqkvt = (__hip_bfloat16*)alloc((size_t)NQ * Cc * 2);
    __hip_bfloat16* qkv   = (__hip_bfloat16*)alloc((size_t)Mtot * NQ * 2);
    __hip_bfloat16* aout  = (__hip_bfloat16*)alloc((size_t)Mtot * Cc * 2);
    __hip_bfloat16* wot   = (__hip_bfloat16*)alloc((size_t)Cc * Cc * 2);
    __hip_bfloat16* yln   = (__hip_bfloat16*)alloc((size_t)Mtot * Cc * 2);
    __hip_bfloat16* w1b   = (__hip_bfloat16*)alloc((size_t)CffP * Cc * 2);
    float*          b1p   = (float*)alloc((size_t)CffP * 4);
    __hip_bfloat16* mid   = (__hip_bfloat16*)alloc((size_t)Mtot * CffP * 2);
    __hip_bfloat16* w2b   = (__hip_bfloat16*)alloc((size_t)Cc * CffP * 2);
    __hip_bfloat16* f2o3  = (__hip_bfloat16*)alloc((size_t)3 * Mtot * Cc * 2);

    if (ws_size < off) {
        sentinel_kernel<<<1, 256, 0, stream>>>((float*)d_out, (float)off * 1e-6f);
        return;
    }

    // merged transpose + weight prep (one dispatch)
    {
        constexpr int TBLK = (HW / 32) * (Cc / 32) * Bn;   // 5184
        const int prep_total = NQ * Cc + Cc * Cc + CffP * Cc + Cc * CffP + CffP;
        const int grid = TBLK + (prep_total + 255) / 256;
        prologue<<<grid, 256, 0, stream>>>(
            x, xlb, WQ, WK, WV, WO, f1w, f2w, f1b, wqkvt, wot, w1b, w2b, b1p);
    }

    // QKV: (M x 288) * (288 x 864) -> bf16, 96x96 tiles (grid 1728 = 6.75/CU)
    gemm_mfma<96, 96, true, false, false><<<dim3(NQ / 96, Mtot / 96, 1), 256, 0, stream>>>(
        xlb, wqkvt, nullptr, qkv, Mtot, NQ, Cc, Cc);

    // attention over ALL pixels (border pixels write zeros; replaces memset)
    attn_kernel<<<(Mtot * 9 * 8) / 256, 256, 0, stream>>>(qkv, aout);

    // W_O + LN1 + ReLU fused: yln = bf16(relu(LN(aout * WO)))
    gemm_ln<false><<<Mtot / 32, 256, 0, stream>>>(
        aout, wot, nullptr, g1, b1, yln, Cc);

    // FFN1: (M x 288) * (288 x 2688) + b1, relu -> bf16 (grid 3024)
    gemm_mfma<128, 128, true, true, true><<<dim3(CffP / 128, Mtot / 128, 1), 256, 0, stream>>>(
        yln, w1b, b1p, mid, Mtot, CffP, Cc, Cc);

    // FFN2: (M x 2688) * (2688 x 288) -> 3 bf16 partial planes, split-K (grid 1728)
    gemm_mfma<96, 96, true, false, false><<<dim3(Cc / 96, Mtot / 96, 3), 256, 0, stream>>>(
        mid, w2b, nullptr, f2o3, Mtot, Cc, CffP / 3, CffP);

    // 3-plane reduce + b2 + LN2 + residual + ReLU + coalesced transpose out
    final_kernel<<<Mtot / 32, 256, 0, stream>>>(f2o3, f2b, xlb, g2, b2, (float*)d_out);
}